// Round 10
// baseline (296.815 us; speedup 1.0000x reference)
//
#include <hip/hip_runtime.h>
#include <hip/hip_bf16.h>

#define BB 16
#define DDIM 256
#define TLEN 4096
#define KCODES 1024
#define NQ (BB*TLEN)   // 65536
#define QB 64          // queries per k_mdist block
#define MAXC 32

#define FLT_MAX_C 3.402823466e+38f

using short8 = __attribute__((ext_vector_type(8))) short;
using f32x4  = __attribute__((ext_vector_type(4))) float;

// RNE fp32 -> bf16 (bit pattern), and back
__device__ __forceinline__ unsigned short f2bf(float x) {
  unsigned u = __float_as_uint(x);
  unsigned r = (u + 0x7fffu + ((u >> 16) & 1u)) >> 16;
  return (unsigned short)r;
}
__device__ __forceinline__ float bf2f(unsigned short h) {
  return __uint_as_float(((unsigned)h) << 16);
}

// ---------------------------------------------------------------------------
// numpy pairwise 8-accumulator block over 128 elements (one half of n=256).
// np_sumsq_256(x) == fadd(np_sumsq_128(x), np_sumsq_128(x+128)) exactly.
// ---------------------------------------------------------------------------
__device__ __forceinline__ float np_sumsq_128(const float* q, int stride) {
  float r[8];
#pragma unroll
  for (int j = 0; j < 8; ++j) {
    float v = q[(size_t)j * (size_t)stride];
    r[j] = __fmul_rn(v, v);
  }
  for (int i = 8; i < 128; i += 8) {
#pragma unroll
    for (int j = 0; j < 8; ++j) {
      float v = q[(size_t)(i + j) * (size_t)stride];
      r[j] = __fadd_rn(r[j], __fmul_rn(v, v));
    }
  }
  return __fadd_rn(__fadd_rn(__fadd_rn(r[0], r[1]), __fadd_rn(r[2], r[3])),
                   __fadd_rn(__fadd_rn(r[4], r[5]), __fadd_rn(r[6], r[7])));
}
__device__ __forceinline__ float np_sumsq_256s(const float* p, int stride) {
  return __fadd_rn(np_sumsq_128(p, stride),
                   np_sumsq_128(p + (size_t)128 * stride, stride));
}

// ---------------------------------------------------------------------------
// k_prep: embT (for gather), e2 exact, bf16-hi split of emb [k][d],
// maxe = max|e| (rigorous bound input for the filter).
// ---------------------------------------------------------------------------
__global__ void k_prep(const float* __restrict__ emb, float* __restrict__ embT,
                       float* __restrict__ e2, short* __restrict__ ebh,
                       unsigned* __restrict__ maxe) {
  const int k = blockIdx.x;
  const int d = threadIdx.x;
  __shared__ float row[DDIM];
  float v = emb[(size_t)k * DDIM + d];
  row[d] = v;
  embT[(size_t)d * KCODES + k] = v;
  ebh[(size_t)k * DDIM + d] = (short)f2bf(v);
  float a = fabsf(v);
#pragma unroll
  for (int m = 1; m < 64; m <<= 1) a = fmaxf(a, __shfl_xor(a, m, 64));
  if ((threadIdx.x & 63) == 0) atomicMax(maxe, __float_as_uint(a));
  __syncthreads();
  if (d == 0) e2[k] = np_sumsq_256s(row, 1);
}

// ---------------------------------------------------------------------------
// k_mdist v6: 1024 threads = 16 waves; block = 64 queries x 1024 codes.
// Wave w: q-half qh=w>>3 (32 q), code base kb=(w&7)*128. acc[2][8] f32x4
// = 64 regs; __launch_bounds__(1024,4) -> 128-reg cap, 4 waves/SIMD.
// z staged in two 32KB halves (z2/sabs computed per-half with the exact
// numpy split); A-frags (bf16-hi) built once into LDS (32KB). B streams
// from L2 with an 8-deep rotating register prefetch (one ks ahead).
// Epilogue: per-query rigorous window DELTA_q = 0.009*maxe*sabs_q + 2e-4,
// then exact fp32 recheck (reference chain, z from global) -> bit-exact
// first-occurrence argmin. Epilogue arrays alias the z-stage region.
// ---------------------------------------------------------------------------
__global__ __launch_bounds__(1024, 4)
void k_mdist(const float* __restrict__ z, const float* __restrict__ emb,
             const short* __restrict__ ebh, const float* __restrict__ e2,
             const unsigned* __restrict__ maxeU, int* __restrict__ idx,
             float* __restrict__ oidx, int* __restrict__ hist,
             double* __restrict__ lossp) {
  __shared__ __align__(16) char zbuf[32768];   // zf [128][64] / epilogue alias
  __shared__ __align__(16) short8 abh[2048];   // [8ks][4mt][64lane], 32KB
  __shared__ float z2s[QB];
  __shared__ float sabs[QB];
  float* zf   = (float*)zbuf;
  // epilogue aliases (zf dead after A-build + z2 phases):
  float* sm   = (float*)zbuf;                  // [16][32]  2KB
  float* qmin = (float*)(zbuf + 2048);         // [64]
  int*   cnt  = (int*)(zbuf + 2304);           // [64]
  int*   ovf  = (int*)(zbuf + 2560);           // [64]
  int*   cand = (int*)(zbuf + 2816);           // [64][MAXC] 8KB
  float* bd   = (float*)(zbuf + 11008);        // [64][16]   4KB
  int*   bk   = (int*)(zbuf + 15104);          // [64][16]   4KB

  const int tid = threadIdx.x;
  const int lane = tid & 63;
  const int w = tid >> 6;    // 0..15
  const int g = lane >> 4;   // 0..3
  const int c = lane & 15;
  const int qh = w >> 3;     // 0..1  (q-half)
  const int kb = (w & 7) * 128;
  const int n0 = blockIdx.x * QB;
  const float* zp = z + (size_t)(n0 >> 12) * DDIM * TLEN + (n0 & (TLEN - 1));

  float th0 = 0.f, sa0 = 0.f;

  // ---- two-phase stage + A-build + z2/sabs ----
#pragma unroll
  for (int h = 0; h < 2; ++h) {
    // stage zf[d_local][q] for d in [h*128, h*128+128)
#pragma unroll
    for (int i = 0; i < 2; ++i) {
      int s4 = i * 1024 + tid;           // 2048 float4 slots
      int dl = s4 >> 4, q4 = (s4 & 15) * 4;
      *(float4*)&zf[dl * QB + q4] =
          *(const float4*)(zp + (size_t)(h * 128 + dl) * TLEN + q4);
    }
    __syncthreads();
    // build A-frags for ks in [4h, 4h+4): slot s = h*1024 + tid
    {
      int s = h * 1024 + tid;
      int mt = (s >> 6) & 3, ln = s & 63;
      int q = mt * 16 + (ln & 15);
      int d0l = ((s >> 8) & 3) * 32 + (ln >> 4) * 8;  // local d within half
      short8 hh;
#pragma unroll
      for (int j = 0; j < 8; ++j) hh[j] = (short)f2bf(zf[(d0l + j) * QB + q]);
      abh[s] = hh;
    }
    // z2/sabs partials (exact numpy split: th per 128-half)
    if (tid < QB) {
      float th = np_sumsq_128(&zf[tid], QB);
      float sa = 0.f;
      for (int d = 0; d < 128; ++d) sa += fabsf(zf[d * QB + tid]);
      if (h == 0) { th0 = th; sa0 = sa; }
      else {
        z2s[tid] = __fadd_rn(th0, th);
        sabs[tid] = sa0 + sa;
      }
    }
    __syncthreads();
  }

  // ---- MFMA main loop: 8-deep rotating B prefetch ----
  f32x4 acc[2][8];
#pragma unroll
  for (int mt = 0; mt < 2; ++mt)
#pragma unroll
    for (int nt = 0; nt < 8; ++nt) {
      f32x4 zz = {0.f, 0.f, 0.f, 0.f};
      acc[mt][nt] = zz;
    }

  const short* ebp = ebh + (size_t)(kb + c) * DDIM + g * 8;
  short8 bbuf[8];
#pragma unroll
  for (int nt = 0; nt < 8; ++nt)
    bbuf[nt] = *(const short8*)(ebp + nt * (16 * DDIM));

  for (int ks = 0; ks < 8; ++ks) {
    short8 ah0 = abh[ks * 256 + (qh * 2 + 0) * 64 + lane];
    short8 ah1 = abh[ks * 256 + (qh * 2 + 1) * 64 + lane];
    const int ksn = (ks + 1) & 7;
#pragma unroll
    for (int nt = 0; nt < 8; ++nt) {
      short8 b = bbuf[nt];
      bbuf[nt] = *(const short8*)(ebp + nt * (16 * DDIM) + ksn * 32);
      acc[0][nt] = __builtin_amdgcn_mfma_f32_16x16x32_bf16(ah0, b, acc[0][nt], 0, 0, 0);
      acc[1][nt] = __builtin_amdgcn_mfma_f32_16x16x32_bf16(ah1, b, acc[1][nt], 0, 0, 0);
    }
  }

  // ---- epilogue: per-thread min -> wave min -> block min ----
  const float maxe = __uint_as_float(*maxeU);
  float e2c[8];
#pragma unroll
  for (int nt = 0; nt < 8; ++nt) e2c[nt] = e2[kb + nt * 16 + c];

  float smin[2][4];
#pragma unroll
  for (int mt = 0; mt < 2; ++mt)
#pragma unroll
    for (int r = 0; r < 4; ++r) {
      float m = FLT_MAX_C;
#pragma unroll
      for (int nt = 0; nt < 8; ++nt)
        m = fminf(m, e2c[nt] - 2.0f * acc[mt][nt][r]);
#pragma unroll
      for (int s = 1; s < 16; s <<= 1) m = fminf(m, __shfl_xor(m, s, 64));
      smin[mt][r] = m;
    }
  // zf region is dead now; write sm / init cnt,ovf
  if (c == 0) {
#pragma unroll
    for (int mt = 0; mt < 2; ++mt)
#pragma unroll
      for (int r = 0; r < 4; ++r)
        sm[w * 32 + mt * 16 + g * 4 + r] = smin[mt][r];
  }
  if (tid < QB) { cnt[tid] = 0; ovf[tid] = 0; }
  __syncthreads();
  if (tid < QB) {
    const int qq = tid >> 5, j = tid & 31;
    float m = sm[(qq * 8) * 32 + j];
#pragma unroll
    for (int kg = 1; kg < 8; ++kg) m = fminf(m, sm[(qq * 8 + kg) * 32 + j]);
    qmin[tid] = m;
  }
  __syncthreads();

  // ---- candidate collection (per-query rigorous window) ----
#pragma unroll
  for (int mt = 0; mt < 2; ++mt)
#pragma unroll
    for (int r = 0; r < 4; ++r) {
      const int ql = qh * 32 + mt * 16 + g * 4 + r;
      const float lim = qmin[ql] + (maxe * sabs[ql]) * 0.009f + 2e-4f;
#pragma unroll
      for (int nt = 0; nt < 8; ++nt) {
        float s = e2c[nt] - 2.0f * acc[mt][nt][r];
        if (s <= lim) {
          int p = atomicAdd(&cnt[ql], 1);
          if (p < MAXC) cand[ql * MAXC + p] = kb + nt * 16 + c;
          else ovf[ql] = 1;
        }
      }
    }
  __syncthreads();

  // ---- exact recheck (reference fp32 chain; z from global), 16 slots/q ----
  {
    const int q = tid & 63;
    const int slot = tid >> 6;
    const float z2q = z2s[q];
    const float* zq = zp + q;   // stride TLEN over d
    float bestd = FLT_MAX_C;
    int besti = (1 << 30);
    const bool all = (ovf[q] != 0) || (cnt[q] > MAXC);
    const int count = all ? KCODES : cnt[q];
    for (int ci = slot; ci < count; ci += 16) {
      const int k = all ? ci : cand[q * MAXC + ci];
      const float* ek = emb + (size_t)k * DDIM;
      float a0 = 0.f;
      for (int d = 0; d < DDIM; ++d)
        a0 = __fmaf_rn(zq[(size_t)d * TLEN], ek[d], a0);
      float dist = __fsub_rn(__fadd_rn(z2q, e2[k]), __fmul_rn(2.0f, a0));
      if (dist < bestd || (dist == bestd && k < besti)) { bestd = dist; besti = k; }
    }
    bd[q * 16 + slot] = bestd;
    bk[q * 16 + slot] = besti;
  }
  __syncthreads();

  if (tid < QB) {
    float B = bd[tid * 16 + 0];
    int K = bk[tid * 16 + 0];
#pragma unroll
    for (int s = 1; s < 16; ++s) {
      float d2 = bd[tid * 16 + s];
      int k2 = bk[tid * 16 + s];
      if (d2 < B || (d2 == B && k2 < K)) { B = d2; K = k2; }
    }
    K &= (KCODES - 1);
    idx[n0 + tid] = K;
    oidx[n0 + tid] = (float)K;
    atomicAdd(&hist[K], 1);
    double ls = (double)B;
#pragma unroll
    for (int m = 1; m < 64; m <<= 1) ls += __shfl_xor(ls, m, 64);
    if (tid == 0) lossp[blockIdx.x] = ls;
  }
}

// ---------------------------------------------------------------------------
// k_gather: out[b,d,t] = emb[idx[b,t], d]; one block per (b,d); float4 stores
// ---------------------------------------------------------------------------
__global__ void k_gather(const float* __restrict__ embT,
                         const int* __restrict__ idx,
                         float* __restrict__ out) {
  __shared__ float er[KCODES];
  const int blk = blockIdx.x;  // b*D + d
  const int bq = blk >> 8;
  const int d = blk & 255;
  const int tid = threadIdx.x;
  *((float4*)&er[tid * 4]) =
      *((const float4*)(embT + (size_t)d * KCODES + tid * 4));
  __syncthreads();
  const int* ip = idx + (size_t)bq * TLEN;
  float* op = out + (size_t)blk * TLEN;
#pragma unroll
  for (int cch = 0; cch < 4; ++cch) {
    int t0 = cch * 1024 + tid * 4;
    int4 ii = *(const int4*)&ip[t0];
    float4 v;
    v.x = er[ii.x & (KCODES - 1)];
    v.y = er[ii.y & (KCODES - 1)];
    v.z = er[ii.z & (KCODES - 1)];
    v.w = er[ii.w & (KCODES - 1)];
    *(float4*)&op[t0] = v;
  }
}

// ---------------------------------------------------------------------------
// k_final: loss and perplexity (deterministic fixed-tree reductions)
// lossp: 1024 per-block partials.
// ---------------------------------------------------------------------------
__global__ void k_final(const int* __restrict__ hist,
                        const double* __restrict__ lossp,
                        float* __restrict__ out2) {
  const int tid = threadIdx.x;  // 256
  double ls = 0.0;
  for (int i = 0; i < 4; ++i) ls += lossp[tid * 4 + i];
  float es = 0.f;
  for (int i = tid; i < KCODES; i += 256) {
    float p = (float)hist[i] / 65536.0f;
    es += p * logf(p + 1e-10f);
  }
#pragma unroll
  for (int m = 1; m < 64; m <<= 1) {
    ls += __shfl_xor(ls, m, 64);
    es += __shfl_xor(es, m, 64);
  }
  __shared__ double lw[4];
  __shared__ float ew[4];
  if ((tid & 63) == 0) { lw[tid >> 6] = ls; ew[tid >> 6] = es; }
  __syncthreads();
  if (tid == 0) {
    double lt = lw[0] + lw[1] + lw[2] + lw[3];
    float et = ew[0] + ew[1] + ew[2] + ew[3];
    float loss = 0.25f * (float)(lt / (double)((long long)NQ * DDIM));
    float perp = expf(-et);
    out2[0] = loss;
    out2[1] = perp;
  }
}

// ---------------------------------------------------------------------------
// workspace layout (bytes):
//   embT  : 0        .. 1048576   (D*K floats)
//   e2    : 1048576  .. 1052672   (K floats)
//   idx   : 1052672  .. 1314816   (N ints)
//   hist  : 1314816  .. 1318912   (K ints)        <- memset each launch
//   maxe  : 1318912  .. 1318916   (1 uint)        <- memset with hist
//   lossp : 1318920  .. 1327112   (1024 doubles)  <- fully written
//   ebh   : 1327120  .. 1851408   (K*D bf16 hi)
// total ~1.85 MB
// ---------------------------------------------------------------------------
extern "C" void kernel_launch(void* const* d_in, const int* in_sizes, int n_in,
                              void* d_out, int out_size, void* d_ws, size_t ws_size,
                              hipStream_t stream) {
  const float* z = (const float*)d_in[0];
  const float* emb = (const float*)d_in[1];
  float* out = (float*)d_out;

  char* ws = (char*)d_ws;
  float* embT = (float*)(ws);
  float* e2 = (float*)(ws + 1048576);
  int* idx = (int*)(ws + 1052672);
  int* hist = (int*)(ws + 1314816);
  unsigned* maxe = (unsigned*)(ws + 1318912);
  double* lossp = (double*)(ws + 1318920);
  short* ebh = (short*)(ws + 1327120);

  float* oidx = out + ((size_t)out_size - 2 - NQ);
  float* out2 = out + ((size_t)out_size - 2);

  hipMemsetAsync(hist, 0, KCODES * sizeof(int) + sizeof(unsigned), stream);

  k_prep<<<KCODES, 256, 0, stream>>>(emb, embT, e2, ebh, maxe);
  k_mdist<<<NQ / QB, 1024, 0, stream>>>(z, emb, ebh, e2, maxe, idx, oidx,
                                        hist, lossp);
  k_gather<<<BB * DDIM, 256, 0, stream>>>(embT, idx, out);
  k_final<<<1, 256, 0, stream>>>(hist, lossp, out2);
}

// Round 11
// 254.590 us; speedup vs baseline: 1.1659x; 1.1659x over previous
//
#include <hip/hip_runtime.h>
#include <hip/hip_bf16.h>

#define BB 16
#define DDIM 256
#define TLEN 4096
#define KCODES 1024
#define NQ (BB*TLEN)   // 65536
#define QB 64          // queries per k_mdist block
#define MAXC 32

#define FLT_MAX_C 3.402823466e+38f

using short8 = __attribute__((ext_vector_type(8))) short;
using f32x4  = __attribute__((ext_vector_type(4))) float;

// RNE fp32 -> bf16 (bit pattern)
__device__ __forceinline__ unsigned short f2bf(float x) {
  unsigned u = __float_as_uint(x);
  unsigned r = (u + 0x7fffu + ((u >> 16) & 1u)) >> 16;
  return (unsigned short)r;
}

// ---------------------------------------------------------------------------
// numpy pairwise 8-accumulator block over 128 elements (half of n=256).
// np_sumsq_256(x) == fadd(block(x), block(x+128)) exactly.
// ---------------------------------------------------------------------------
__device__ __forceinline__ float np_sumsq_128(const float* q, int stride) {
  float r[8];
#pragma unroll
  for (int j = 0; j < 8; ++j) {
    float v = q[(size_t)j * (size_t)stride];
    r[j] = __fmul_rn(v, v);
  }
  for (int i = 8; i < 128; i += 8) {
#pragma unroll
    for (int j = 0; j < 8; ++j) {
      float v = q[(size_t)(i + j) * (size_t)stride];
      r[j] = __fadd_rn(r[j], __fmul_rn(v, v));
    }
  }
  return __fadd_rn(__fadd_rn(__fadd_rn(r[0], r[1]), __fadd_rn(r[2], r[3])),
                   __fadd_rn(__fadd_rn(r[4], r[5]), __fadd_rn(r[6], r[7])));
}
__device__ __forceinline__ float np_sumsq_256s(const float* p, int stride) {
  return __fadd_rn(np_sumsq_128(p, stride),
                   np_sumsq_128(p + (size_t)128 * stride, stride));
}

// ---------------------------------------------------------------------------
// k_prep: e2 exact, bf16-hi of emb [k][d], maxe = max|e| (bound input)
// ---------------------------------------------------------------------------
__global__ void k_prep(const float* __restrict__ emb, float* __restrict__ e2,
                       short* __restrict__ ebh, unsigned* __restrict__ maxe) {
  const int k = blockIdx.x;
  const int d = threadIdx.x;
  __shared__ float row[DDIM];
  float v = emb[(size_t)k * DDIM + d];
  row[d] = v;
  ebh[(size_t)k * DDIM + d] = (short)f2bf(v);
  float a = fabsf(v);
#pragma unroll
  for (int m = 1; m < 64; m <<= 1) a = fmaxf(a, __shfl_xor(a, m, 64));
  if ((threadIdx.x & 63) == 0) atomicMax(maxe, __float_as_uint(a));
  __syncthreads();
  if (d == 0) e2[k] = np_sumsq_256s(row, 1);
}

// ---------------------------------------------------------------------------
// k_mdist v7: 1024 threads = 16 waves, block = 64 queries x 1024 codes.
// Wave w: ALL 64 q x codes [w*64, w*64+64). acc[4][4] f32x4 = 64 VGPR;
// ah[4]=16, bbuf[4] (4-deep rotating B prefetch, one ks ahead)=16 ->
// peak live ~112 <= cap 128 (__launch_bounds__(1024,1): 1 block/CU,
// 4 waves/SIMD). Each B 16B load feeds 4 MFMAs; one codebook pass/block.
// zf (exact fp32 z tile, 64KB) stays live for the whole kernel; epilogue
// arrays alias only the dead A-frag region. Fused: oidx write + output
// gather (coalesced 256B stores, emb rows from L2).
// Filter exactness: one MFMA pass (zh*eh), rigorous per-query window
// DELTA_q = 0.009*maxe*sabs_q + 2e-4, exact fp32 recheck (reference
// rounding chain, z from LDS) -> bit-exact first-occurrence argmin.
// Dynamic LDS 99584B: zf 64K | abh 32K (aliased) | tail 1.25K.
// ---------------------------------------------------------------------------
__global__ __launch_bounds__(1024, 1)
void k_mdist(const float* __restrict__ z, const float* __restrict__ emb,
             const short* __restrict__ ebh, const float* __restrict__ e2,
             const unsigned* __restrict__ maxeU, float* __restrict__ out,
             float* __restrict__ oidx, int* __restrict__ hist,
             double* __restrict__ lossp) {
  extern __shared__ __align__(16) char sbuf[];        // 99584 bytes
  float*  zf   = (float*)sbuf;                        // [256][64], live always
  short8* abh  = (short8*)(sbuf + 65536);             // [8ks][4mt][64lane]
  // aliases into abh region (valid after post-MFMA barrier):
  float* sm    = (float*)(sbuf + 65536);              // [16][64]  4KB
  float* qmin  = (float*)(sbuf + 65536 + 4096);       // [64]
  int*   cand  = (int*)(sbuf + 65536 + 4352);         // [64][MAXC] 8KB
  float* bd    = (float*)(sbuf + 65536 + 12544);      // [64][16]   4KB
  int*   bk    = (int*)(sbuf + 65536 + 16640);        // [64][16]   4KB
  // tail (never aliased):
  float* z2s   = (float*)(sbuf + 98304);              // [64]
  float* sabs  = (float*)(sbuf + 98304 + 256);        // [64]
  int*   cnt   = (int*)(sbuf + 98304 + 512);          // [64]
  int*   ovf   = (int*)(sbuf + 98304 + 768);          // [64]
  int*   sidxs = (int*)(sbuf + 98304 + 1024);         // [64]

  const int tid = threadIdx.x;
  const int lane = tid & 63;
  const int w = tid >> 6;    // 0..15
  const int g = lane >> 4;   // 0..3
  const int c = lane & 15;
  const int kb = w * 64;     // wave's code base
  const int n0 = blockIdx.x * QB;
  const int b = n0 >> 12;
  const int t0 = n0 & (TLEN - 1);
  const float* zp = z + (size_t)b * DDIM * TLEN + t0;

  // ---- 1. stage zf[d][q] (exact fp32), coalesced float4 ----
#pragma unroll
  for (int i = 0; i < 4; ++i) {
    int s4 = i * 1024 + tid;           // 4096 float4 slots
    int dl = s4 >> 4, q4 = (s4 & 15) * 4;
    *(float4*)&zf[dl * QB + q4] = *(const float4*)(zp + (size_t)dl * TLEN + q4);
  }
  __syncthreads();

  // ---- 2. A-build (all threads) + z2/sabs + cnt/ovf init (tail) ----
#pragma unroll
  for (int i = 0; i < 2; ++i) {
    int s = i * 1024 + tid;            // 2048 slots: ks(8) x mt(4) x lane(64)
    int ks = s >> 8, mt = (s >> 6) & 3, ln = s & 63;
    int q = mt * 16 + (ln & 15);
    int d0 = ks * 32 + (ln >> 4) * 8;
    short8 hh;
#pragma unroll
    for (int j = 0; j < 8; ++j) hh[j] = (short)f2bf(zf[(d0 + j) * QB + q]);
    abh[s] = hh;
  }
  if (tid < QB) {
    z2s[tid] = np_sumsq_256s(&zf[tid], QB);
    float sa = 0.f;
    for (int d = 0; d < DDIM; ++d) sa += fabsf(zf[d * QB + tid]);
    sabs[tid] = sa;
    cnt[tid] = 0;
    ovf[tid] = 0;
  }
  __syncthreads();

  // ---- 3. MFMA main loop (one pass, 4-deep rotating B prefetch) ----
  f32x4 acc[4][4];
#pragma unroll
  for (int mt = 0; mt < 4; ++mt)
#pragma unroll
    for (int nt = 0; nt < 4; ++nt) {
      f32x4 zz = {0.f, 0.f, 0.f, 0.f};
      acc[mt][nt] = zz;
    }

  const short* ebp = ebh + (size_t)(kb + c) * DDIM + g * 8;
  short8 bbuf[4];
#pragma unroll
  for (int nt = 0; nt < 4; ++nt)
    bbuf[nt] = *(const short8*)(ebp + nt * (16 * DDIM));

  for (int ks = 0; ks < 8; ++ks) {
    short8 ah[4];
#pragma unroll
    for (int mt = 0; mt < 4; ++mt) ah[mt] = abh[ks * 256 + mt * 64 + lane];
    const int ksn = (ks + 1) & 7;
#pragma unroll
    for (int nt = 0; nt < 4; ++nt) {
      short8 bv = bbuf[nt];
      bbuf[nt] = *(const short8*)(ebp + nt * (16 * DDIM) + ksn * 32);
#pragma unroll
      for (int mt = 0; mt < 4; ++mt)
        acc[mt][nt] =
            __builtin_amdgcn_mfma_f32_16x16x32_bf16(ah[mt], bv, acc[mt][nt], 0, 0, 0);
    }
  }
  __syncthreads();  // abh dead -> alias region writable

  // ---- 4. per-(q) wave-min over this wave's 64 codes ----
  const float maxe = __uint_as_float(*maxeU);
  float e2c[4];
#pragma unroll
  for (int nt = 0; nt < 4; ++nt) e2c[nt] = e2[kb + nt * 16 + c];

#pragma unroll
  for (int mt = 0; mt < 4; ++mt) {
    float m4[4];
#pragma unroll
    for (int r = 0; r < 4; ++r) {
      float m = FLT_MAX_C;
#pragma unroll
      for (int nt = 0; nt < 4; ++nt)
        m = fminf(m, e2c[nt] - 2.0f * acc[mt][nt][r]);
#pragma unroll
      for (int s = 1; s < 16; s <<= 1) m = fminf(m, __shfl_xor(m, s, 64));
      m4[r] = m;
    }
    if (c == 0) {
#pragma unroll
      for (int r = 0; r < 4; ++r) sm[w * 64 + mt * 16 + g * 4 + r] = m4[r];
    }
  }
  __syncthreads();
  if (tid < QB) {
    float m = sm[tid];
#pragma unroll
    for (int wv = 1; wv < 16; ++wv) m = fminf(m, sm[wv * 64 + tid]);
    qmin[tid] = m;
  }
  __syncthreads();

  // ---- 5. candidate collection (per-query rigorous window) ----
#pragma unroll
  for (int mt = 0; mt < 4; ++mt)
#pragma unroll
    for (int r = 0; r < 4; ++r) {
      const int ql = mt * 16 + g * 4 + r;
      const float lim = qmin[ql] + (maxe * sabs[ql]) * 0.009f + 2e-4f;
#pragma unroll
      for (int nt = 0; nt < 4; ++nt) {
        float s = e2c[nt] - 2.0f * acc[mt][nt][r];
        if (s <= lim) {
          int p = atomicAdd(&cnt[ql], 1);
          if (p < MAXC) cand[ql * MAXC + p] = kb + nt * 16 + c;
          else ovf[ql] = 1;
        }
      }
    }
  __syncthreads();

  // ---- 6. exact recheck (reference fp32 chain; z from LDS), 16 slots/q ----
  {
    const int q = tid & 63;
    const int slot = tid >> 6;
    const float z2q = z2s[q];
    float bestd = FLT_MAX_C;
    int besti = (1 << 30);
    const bool all = (ovf[q] != 0) || (cnt[q] > MAXC);
    const int count = all ? KCODES : cnt[q];
    for (int ci = slot; ci < count; ci += 16) {
      const int k = all ? ci : cand[q * MAXC + ci];
      const float4* ek = (const float4*)(emb + (size_t)k * DDIM);
      float a0 = 0.f;
      for (int dd = 0; dd < 64; ++dd) {
        float4 e4 = ek[dd];
        a0 = __fmaf_rn(zf[(dd * 4 + 0) * QB + q], e4.x, a0);
        a0 = __fmaf_rn(zf[(dd * 4 + 1) * QB + q], e4.y, a0);
        a0 = __fmaf_rn(zf[(dd * 4 + 2) * QB + q], e4.z, a0);
        a0 = __fmaf_rn(zf[(dd * 4 + 3) * QB + q], e4.w, a0);
      }
      float dist = __fsub_rn(__fadd_rn(z2q, e2[k]), __fmul_rn(2.0f, a0));
      if (dist < bestd || (dist == bestd && k < besti)) { bestd = dist; besti = k; }
    }
    bd[q * 16 + slot] = bestd;
    bk[q * 16 + slot] = besti;
  }
  __syncthreads();

  // ---- 7. final per-query reduce; idx/loss/hist outputs ----
  if (tid < QB) {
    float B = bd[tid * 16 + 0];
    int K = bk[tid * 16 + 0];
#pragma unroll
    for (int s = 1; s < 16; ++s) {
      float d2 = bd[tid * 16 + s];
      int k2 = bk[tid * 16 + s];
      if (d2 < B || (d2 == B && k2 < K)) { B = d2; K = k2; }
    }
    K &= (KCODES - 1);
    sidxs[tid] = K;
    oidx[n0 + tid] = (float)K;
    atomicAdd(&hist[K], 1);
    double ls = (double)B;
#pragma unroll
    for (int m = 1; m < 64; m <<= 1) ls += __shfl_xor(ls, m, 64);
    if (tid == 0) lossp[blockIdx.x] = ls;
  }
  __syncthreads();

  // ---- 8. fused gather: out[b,d,t0+q] = emb[sidxs[q]][d] ----
  float* obase = out + (size_t)b * DDIM * TLEN + t0;
#pragma unroll
  for (int i = 0; i < 16; ++i) {
    int e = i * 1024 + tid;   // 16384 elements
    int q = e & 63, d = e >> 6;
    obase[(size_t)d * TLEN + q] = emb[(size_t)sidxs[q] * DDIM + d];
  }
}

// ---------------------------------------------------------------------------
// k_final: loss and perplexity (deterministic fixed-tree reductions)
// ---------------------------------------------------------------------------
__global__ void k_final(const int* __restrict__ hist,
                        const double* __restrict__ lossp,
                        float* __restrict__ out2) {
  const int tid = threadIdx.x;  // 256
  double ls = 0.0;
  for (int i = 0; i < 4; ++i) ls += lossp[tid * 4 + i];  // 1024 partials
  float es = 0.f;
  for (int i = tid; i < KCODES; i += 256) {
    float p = (float)hist[i] / 65536.0f;
    es += p * logf(p + 1e-10f);
  }
#pragma unroll
  for (int m = 1; m < 64; m <<= 1) {
    ls += __shfl_xor(ls, m, 64);
    es += __shfl_xor(es, m, 64);
  }
  __shared__ double lw[4];
  __shared__ float ew[4];
  if ((tid & 63) == 0) { lw[tid >> 6] = ls; ew[tid >> 6] = es; }
  __syncthreads();
  if (tid == 0) {
    double lt = lw[0] + lw[1] + lw[2] + lw[3];
    float et = ew[0] + ew[1] + ew[2] + ew[3];
    float loss = 0.25f * (float)(lt / (double)((long long)NQ * DDIM));
    float perp = expf(-et);
    out2[0] = loss;
    out2[1] = perp;
  }
}

// ---------------------------------------------------------------------------
// workspace layout (bytes):
//   e2    : 0     .. 4096     (K floats)
//   hist  : 4096  .. 8192     (K ints)     <- memset each launch (with maxe)
//   maxe  : 8192  .. 8196     (1 uint)
//   lossp : 8200  .. 16392    (1024 doubles, fully written)
//   ebh   : 16400 .. 540688   (K*D bf16 hi)
// total ~0.54 MB
// ---------------------------------------------------------------------------
extern "C" void kernel_launch(void* const* d_in, const int* in_sizes, int n_in,
                              void* d_out, int out_size, void* d_ws, size_t ws_size,
                              hipStream_t stream) {
  const float* z = (const float*)d_in[0];
  const float* emb = (const float*)d_in[1];
  float* out = (float*)d_out;

  char* ws = (char*)d_ws;
  float* e2 = (float*)(ws);
  int* hist = (int*)(ws + 4096);
  unsigned* maxe = (unsigned*)(ws + 8192);
  double* lossp = (double*)(ws + 8200);
  short* ebh = (short*)(ws + 16400);

  float* oidx = out + ((size_t)out_size - 2 - NQ);
  float* out2 = out + ((size_t)out_size - 2);

  // dynamic LDS for k_mdist: 99584 bytes
  (void)hipFuncSetAttribute((const void*)k_mdist,
                            hipFuncAttributeMaxDynamicSharedMemorySize,
                            99584);

  hipMemsetAsync(hist, 0, 4100, stream);  // hist + maxe

  k_prep<<<KCODES, 256, 0, stream>>>(emb, e2, ebh, maxe);
  k_mdist<<<NQ / QB, 1024, 99584, stream>>>(z, emb, ebh, e2, maxe, out, oidx,
                                            hist, lossp);
  k_final<<<1, 256, 0, stream>>>(hist, lossp, out2);
}